// Round 9
// baseline (182.011 us; speedup 1.0000x reference)
//
#include <hip/hip_runtime.h>
#include <hip/hip_fp16.h>
#include <math.h>

// Problem constants
#define BB 4
#define HH 48
#define WW 48
#define DD 64
#define CC 2116          // 46*46 true column count (softmax stats)
#define HWp (HH*WW)      // 2304
#define PW 50            // zero-padded field width
#define PP (PW*PW)       // 2500 padded pixels

// slot space: j padded per-row 46->48 -> K width 2208 (dummies are zero)
#define SLOTW 48
#define NSLOT 2208
#define NGRP 276         // 2208/8 groups of 8 slots
#define QW 2304          // F row width (v-domain = 48*48)
#define QROWS 2500       // F rows (u-domain = 50*50)

typedef __attribute__((ext_vector_type(8))) short short8;
typedef __attribute__((ext_vector_type(8))) _Float16 half8;
typedef __attribute__((ext_vector_type(4))) float float4v;

// ---------- workspace layout (byte offsets, all 16B-aligned) ----------
#define OFFB_GPAD  ((size_t)0)            // bf16 [B][2500][64]     1,280,000 B
#define OFFB_BGPAD ((size_t)1280000)      // bf16 [B][2500][64]     1,280,000 B
#define OFFB_E     ((size_t)2560000)      // f32  [B][2304]            36,864 B
#define OFFB_K1D   ((size_t)2596864)      // f32  [B][2208]            35,328 B
#define OFFB_BGT3  ((size_t)2632192)      // fp16 [B][192][2208]    3,391,488 B
#define OFFB_F     ((size_t)6023680)      // fp16 F [B][2500][2304] 46,080,000 B
#define OFFB_CAY   ((size_t)52103680)     // fp16 CAy [B][2304][2208] 40,697,856 B
#define OFFB_ACLP  ((size_t)92801536)     // fp16 [B*2304][8][192]  28,311,552 B
// total 121,113,088 B (ws allocation is 256 MiB)

// ---------- helpers ----------
__device__ __forceinline__ ushort f2bf(float x) {
    unsigned u = __float_as_uint(x);
    return (ushort)((u + 0x7FFFu + ((u >> 16) & 1u)) >> 16);
}

__device__ __forceinline__ float waveReduceSum(float x) {
#pragma unroll
    for (int o = 32; o > 0; o >>= 1) x += __shfl_down(x, o, 64);
    return x;
}

__device__ __forceinline__ __half2 u2h2(uint u) {
    union { uint u; __half2 h; } c; c.u = u; return c.h;
}
__device__ __forceinline__ uint h2u(__half2 h) {
    union { __half2 h; uint u; } c; c.h = h; return c.u;
}

// packed f32x2 -> bf16x2 (RNE), one instruction
__device__ __forceinline__ uint cvtpk_bf16(float lo, float hi) {
    uint r;
    asm("v_cvt_pk_bf16_f32 %0, %1, %2" : "=v"(r) : "v"(lo), "v"(hi));
    return r;
}

// exp(-50*tanh(z)) with tanh folded: = exp(-50 + 100/(e^{2z}+1))
__device__ __forceinline__ float softexp(float d, float mu, float isd) {
    float z = (d - mu) * isd;
    float E2 = __expf(z + z);
    float r = __builtin_amdgcn_rcpf(E2 + 1.f);
    return __expf(fmaf(100.f, r, -50.f));
}

// async 16B global->LDS (wave-uniform LDS base + lane*16)
typedef __attribute__((address_space(3))) void lds_void_t;
typedef __attribute__((address_space(1))) void gmem_void_t;
__device__ __forceinline__ void gld16(const ushort* g, ushort* lds) {
    __builtin_amdgcn_global_load_lds((gmem_void_t*)g, (lds_void_t*)lds, 16, 0, 0);
}

// ---------- build padded fields ----------
__global__ __launch_bounds__(256) void build_pads(const float* __restrict__ g,
                                                  const float* __restrict__ mask,
                                                  ushort* __restrict__ gpad,
                                                  ushort* __restrict__ bgpad,
                                                  float* __restrict__ e) {
    int w = threadIdx.x >> 6, c = threadIdx.x & 63;
    int q4 = blockIdx.x * 4 + w;         // [0, B*2500)
    int b = q4 / PP, q = q4 % PP;
    int yp = q / PW, xp = q % PW;
    size_t o = (size_t)q4 * DD + c;
    if (yp >= 1 && yp <= HH && xp >= 1 && xp <= WW) {
        int pix = (yp - 1) * WW + (xp - 1);
        float gv = g[((size_t)b * HWp + pix) * DD + c];
        float m  = mask[(size_t)b * HWp + pix];
        float bgv = gv * m;
        gpad[o]  = f2bf(gv);
        bgpad[o] = f2bf(bgv);
        float ss = waveReduceSum(bgv * bgv);
        if (c == 0) e[b * HWp + pix] = ss;
    } else {
        gpad[o] = 0;
        bgpad[o] = 0;
    }
}

// ---------- bgT3: fp16 [B][192][2208], row (dx*64+d)[v'] = bgI[v'+dx, d]; + k1d ----------
__global__ __launch_bounds__(256) void build_bgt3_k1d(const ushort* __restrict__ bgpad,
                                                      const float* __restrict__ e,
                                                      ushort* __restrict__ bgT3,
                                                      float* __restrict__ k1d) {
    int b = blockIdx.y;
    int t = threadIdx.x;
    if (blockIdx.x == 35) {
#pragma unroll 1
        for (int st = t; st < NSLOT; st += 256) {
            int jy = st / SLOTW, jx = st - jy * SLOTW;
            float s = 0.f;
            if (jx < 46) {
                const float* eb = e + (size_t)b * HWp + jy * WW + jx;
#pragma unroll
                for (int ddy = 0; ddy < 3; ddy++)
#pragma unroll
                    for (int ddx = 0; ddx < 3; ddx++) s += eb[ddy * WW + ddx];
            }
            k1d[(size_t)b * NSLOT + st] = s;
        }
        return;
    }
    __shared__ ushort T[66 * 65];
    int jt = blockIdx.x;                 // 0..34
    const ushort* src = bgpad + (size_t)b * PP * DD;
    int lr = t >> 3, c8 = (t & 7) * 8;
#pragma unroll
    for (int pass = 0; pass < 2; pass++) {
        int r = lr + pass * 32;
        int v = jt * 64 + r;
        int vy = v / 48, vx = v - vy * 48;
        uint4 d = *(const uint4*)(src + (size_t)((vy + 1) * PW + (vx + 1)) * DD + c8);
        ushort tmp[8];
        *(uint4*)tmp = d;
#pragma unroll
        for (int u = 0; u < 8; u++) {
            float f = __uint_as_float((uint)tmp[u] << 16);
            __half h = __float2half_rn(f);
            T[r * 65 + c8 + u] = *(ushort*)&h;
        }
    }
    if (t < 16) {                        // halo rows 64, 65
        int r = 64 + (t >> 3);
        int c8b = (t & 7) * 8;
        int v = jt * 64 + r;
        int vy = v / 48, vx = v - vy * 48;
        uint4 d = *(const uint4*)(src + (size_t)((vy + 1) * PW + (vx + 1)) * DD + c8b);
        ushort tmp[8];
        *(uint4*)tmp = d;
#pragma unroll
        for (int u = 0; u < 8; u++) {
            float f = __uint_as_float((uint)tmp[u] << 16);
            __half h = __float2half_rn(f);
            T[r * 65 + c8b + u] = *(ushort*)&h;
        }
    }
    __syncthreads();
#pragma unroll
    for (int pass = 0; pass < 2; pass++) {
        int c = lr + pass * 32;
        int j8 = (t & 7) * 8;
        int col0 = jt * 64 + j8;
        if (col0 < NSLOT) {
#pragma unroll
            for (int dx = 0; dx < 3; dx++) {
                ushort tmp[8];
#pragma unroll
                for (int u = 0; u < 8; u++) tmp[u] = T[(j8 + u + dx) * 65 + c];
                *(uint4*)(bgT3 + ((size_t)b * 192 + dx * 64 + c) * NSLOT + col0) =
                    *(const uint4*)tmp;
            }
        }
    }
}

// ---------- fgemm: F[u,v] = sum_dx Q[u+dx,v+dx] as a K=192 GEMM (contiguous k) ----------
__global__ __launch_bounds__(256) void fgemm(const ushort* __restrict__ gpad,
                                             const ushort* __restrict__ bgpad,
                                             __half* __restrict__ Fout) {
    __shared__ ushort As[2 * 4096];
    __shared__ ushort Bs[2 * 4096];
    int i0 = blockIdx.x;
    int b = (i0 & 7) >> 1;                    // batch pinned to XCD pair
    int tile = ((i0 >> 3) << 1) | (i0 & 1);   // 0..359, bijective
    int ty = tile / 18, tx = tile - ty * 18;  // 20 m-tiles x 18 n-tiles
    int m0 = ty * 128, n0 = tx * 128;
    const ushort* Ag = gpad + (size_t)b * PP * DD;
    const ushort* Bg = bgpad + (size_t)b * PP * DD;

    int tid = threadIdx.x;
    int l = tid & 63, w = tid >> 6;
    int quad = l >> 4, l15 = l & 15;
    int sw8 = (l15 >> 1) & 3;
    int wm = (w >> 1) * 64, wn = (w & 1) * 64;
    int rowInC = l >> 2;
    int cSw = (l & 3) ^ ((l >> 3) & 3);

    int baseA[2], baseB[2];
#pragma unroll
    for (int i = 0; i < 2; i++) {
        int rg = w * 2 + i;
        int r = rg * 16 + rowInC;
        int u = m0 + r; if (u > QROWS - 1) u = QROWS - 1;  // clamp; store-guarded
        int n = n0 + r;
        int vy = n / 48, vx = n - vy * 48;
        baseA[i] = u * DD + cSw * 8;
        baseB[i] = ((vy + 1) * PW + (vx + 1)) * DD + cSw * 8;
    }

    float4v acc[4][4];
#pragma unroll
    for (int i = 0; i < 4; i++)
#pragma unroll
        for (int j = 0; j < 4; j++) acc[i][j] = (float4v){0.f, 0.f, 0.f, 0.f};

#pragma unroll
    for (int i = 0; i < 2; i++) {
        int rg = w * 2 + i;
        gld16(Ag + baseA[i], As + rg * 512);
        gld16(Bg + baseB[i], Bs + rg * 512);
    }

    int buf = 0;
    for (int k0 = 0; k0 < 192; k0 += 32) {
        __syncthreads();
        int nb = buf ^ 1;
        if (k0 + 32 < 192) {
#pragma unroll
            for (int i = 0; i < 2; i++) {
                int rg = w * 2 + i;
                gld16(Ag + baseA[i] + (k0 + 32), As + nb * 4096 + rg * 512);
                gld16(Bg + baseB[i] + (k0 + 32), Bs + nb * 4096 + rg * 512);
            }
        }
        const ushort* Ax = As + buf * 4096;
        const ushort* Bx = Bs + buf * 4096;
        short8 af[4], bf[4];
#pragma unroll
        for (int i = 0; i < 4; i++)
            af[i] = *(const short8*)&Ax[(wm + i * 16 + l15) * 32 + ((quad ^ sw8)) * 8];
#pragma unroll
        for (int j = 0; j < 4; j++)
            bf[j] = *(const short8*)&Bx[(wn + j * 16 + l15) * 32 + ((quad ^ sw8)) * 8];
#pragma unroll
        for (int i = 0; i < 4; i++)
#pragma unroll
            for (int j = 0; j < 4; j++)
                acc[i][j] = __builtin_amdgcn_mfma_f32_16x16x32_bf16(af[i], bf[j], acc[i][j], 0, 0, 0);
        buf = nb;
    }

    __half* C = Fout + (size_t)b * QROWS * QW;
#pragma unroll
    for (int i = 0; i < 4; i++) {
#pragma unroll
        for (int j = 0; j < 4; j++) {
            int n = n0 + wn + j * 16 + l15;
#pragma unroll
            for (int r = 0; r < 4; r++) {
                int m = m0 + wm + i * 16 + quad * 4 + r;
                if (m < QROWS) C[(size_t)m * QW + n] = __float2half(acc[i][j][r]);
            }
        }
    }
}

// ---------- qrscay8: fused CS + softmax + dy-combine -> CAy (CA only in LDS) ----------
// Block = 8 output CAy rows (y0..y0+7 at fixed x). Softmax for 10 rows (y0-1..y0+8,
// halo ratio 1.25x vs R8's 1.5x). Normalized fp16 CA rows live in LDS; then
// CAy[y0+p, slot] = sum_dy CAlds[p+2-dy, slot-48dy] (jy>=dy mask).
__global__ __launch_bounds__(320) void qrscay8(const __half* __restrict__ F,
                                               const float* __restrict__ k1d,
                                               ushort* __restrict__ CAy) {
    __shared__ uint smem[11040];           // 44.2 KB: calds 10x2208 fp16; red (20x321 f32) aliases front
    float* red = (float*)smem;
    ushort* calds = (ushort*)smem;

    int i0 = blockIdx.x;                   // 1152 = 8 z x 144
    int b = (i0 & 7) >> 1;                 // batch pinned to XCD pair
    int sub = ((i0 >> 3) << 1) | (i0 & 1); // 0..287, bijective
    int yo = sub / 48, x = sub - yo * 48;
    int y0 = yo * 8;

    int t = threadIdx.x;
    bool act = (t < NGRP);
    int jy = t / 6, jxb = (t - jy * 6) * 8;
    int slot0 = jy * SLOTW + jxb;          // == 8*t for act threads
    bool vc6 = act && (jxb == 40);         // group containing pad slots 46,47

    int rowok[10];
#pragma unroll
    for (int r = 0; r < 10; r++) {
        int yr = y0 - 1 + r;
        rowok[r] = (yr >= 0 && yr < HH) ? 1 : 0;
    }

    float k1v[8] = {0.f, 0.f, 0.f, 0.f, 0.f, 0.f, 0.f, 0.f};
    __half2 cs[10][4];
#pragma unroll
    for (int r = 0; r < 10; r++)
#pragma unroll
        for (int k = 0; k < 4; k++) cs[r][k] = u2h2(0u);

    if (act) {
        const float* k1 = k1d + (size_t)b * NSLOT + slot0;
        float4 ka = *(const float4*)k1;
        float4 kb = *(const float4*)(k1 + 4);
        k1v[0] = ka.x; k1v[1] = ka.y; k1v[2] = ka.z; k1v[3] = ka.w;
        k1v[4] = kb.x; k1v[5] = kb.y; k1v[6] = kb.z; k1v[7] = kb.w;

#pragma unroll
        for (int r = 0; r < 10; r++) {
            if (!rowok[r]) continue;
            int yr = y0 - 1 + r;
            const __half* R = F + ((size_t)b * QROWS + (size_t)yr * PW + x) * QW + slot0;
#pragma unroll
            for (int dy = 0; dy < 3; dy++) {
                uint4 v4 = *(const uint4*)(R + (size_t)dy * PW * QW + 48 * dy);
                cs[r][0] = __hadd2(cs[r][0], u2h2(v4.x));
                cs[r][1] = __hadd2(cs[r][1], u2h2(v4.y));
                cs[r][2] = __hadd2(cs[r][2], u2h2(v4.z));
                cs[r][3] = __hadd2(cs[r][3], u2h2(v4.w));
            }
        }
    }
    // purge pad-slot garbage (slots 46,47 of each jy row)
    if (vc6) {
#pragma unroll
        for (int r = 0; r < 10; r++) cs[r][3] = u2h2(0u);
    }

    // ---- phase A: per-row sum & sumsq of ds = k1 - 2*cs ----
#pragma unroll
    for (int r = 0; r < 10; r++) {
        float s1p = 0.f, s2p = 0.f;
#pragma unroll
        for (int k = 0; k < 4; k++) {
            float2 f = __half22float2(cs[r][k]);
            float d0 = k1v[2*k]   - 2.f * f.x;
            float d1 = k1v[2*k+1] - 2.f * f.y;
            s1p += d0 + d1;
            s2p = fmaf(d0, d0, fmaf(d1, d1, s2p));
        }
        bool live = act && rowok[r];
        red[r * 321 + t]        = live ? s1p : 0.f;
        red[(10 + r) * 321 + t] = live ? s2p : 0.f;
    }
    __syncthreads();
    {
        int v = t >> 4, sb = t & 15;       // all 320 threads: 20 reduce groups
        float s = 0.f;
#pragma unroll
        for (int k = 0; k < 20; k++) s += red[v * 321 + sb + 16 * k];
#pragma unroll
        for (int o = 8; o > 0; o >>= 1) s += __shfl_down(s, o, 16);
        if (sb == 0) red[v * 321 + 320] = s;
    }
    __syncthreads();
    float mu[10], isd[10];
#pragma unroll
    for (int r = 0; r < 10; r++) {
        float m = red[r * 321 + 320] * (1.f / (float)CC);
        float ex2 = red[(10 + r) * 321 + 320] * (1.f / (float)CC);
        mu[r] = m;
        float var = ex2 - m * m;
        isd[r] = rsqrtf(var > 1e-20f ? var : 1e-20f);
    }

    // ---- exp pass: pack unnormalized exp as bf16 pairs (regs), accumulate es ----
    uint eb[10][4];
#pragma unroll
    for (int r = 0; r < 10; r++) {
        float es = 0.f;
#pragma unroll
        for (int k = 0; k < 4; k++) {
            float2 f = __half22float2(cs[r][k]);
            float d0 = k1v[2*k]   - 2.f * f.x;
            float d1 = k1v[2*k+1] - 2.f * f.y;
            if (k == 3 && vc6) { d0 = 1e9f; d1 = 1e9f; }   // pad slots -> ~e^-50 -> 0
            float e0 = softexp(d0, mu[r], isd[r]);
            float e1 = softexp(d1, mu[r], isd[r]);
            es += e0 + e1;
            eb[r][k] = cvtpk_bf16(e0, e1);
        }
        red[r * 321 + t] = (act && rowok[r]) ? es : 0.f;
    }
    __syncthreads();
    if (t < 160) {                         // 10 reduce groups
        int v = t >> 4, sb = t & 15;
        float s = 0.f;
#pragma unroll
        for (int k = 0; k < 20; k++) s += red[v * 321 + sb + 16 * k];
#pragma unroll
        for (int o = 8; o > 0; o >>= 1) s += __shfl_down(s, o, 16);
        if (sb == 0) red[v * 321 + 320] = s;
    }
    __syncthreads();
    float invz[10];
#pragma unroll
    for (int r = 0; r < 10; r++) {
        float z = red[r * 321 + 320];
        invz[r] = __builtin_amdgcn_rcpf(z > 0.f ? z : 1.f);
    }
    __syncthreads();   // all invz read before smem is reused as calds

    // ---- write normalized fp16 CA rows into LDS (zeros for invalid rows) ----
    if (act) {
#pragma unroll
        for (int r = 0; r < 10; r++) {
            uint o[4] = {0u, 0u, 0u, 0u};
            if (rowok[r]) {
#pragma unroll
                for (int k = 0; k < 4; k++) {
                    uint wv = eb[r][k];
                    float lo = __uint_as_float(wv << 16) * invz[r];
                    float hi = __uint_as_float(wv & 0xffff0000u) * invz[r];
                    __half2 hh = __halves2half2(__float2half_rn(lo), __float2half_rn(hi));
                    o[k] = *(uint*)&hh;
                }
            }
            *(uint4*)&calds[(size_t)r * NSLOT + slot0] = *(const uint4*)o;
        }
    }
    __syncthreads();

    // ---- combine: CAy[y0+p, slot] = sum_dy calds[p+2-dy, slot-48dy] ----
    if (act) {
#pragma unroll
        for (int p = 0; p < 8; p++) {
            __half2 a[4];
#pragma unroll
            for (int k = 0; k < 4; k++) a[k] = u2h2(0u);
#pragma unroll
            for (int dy = 0; dy < 3; dy++) {
                if (jy < dy) continue;           // column underflow (group-uniform)
                int r = p + 2 - dy;
                uint4 v4 = *(const uint4*)&calds[(size_t)r * NSLOT + slot0 - 48 * dy];
                a[0] = __hadd2(a[0], u2h2(v4.x));
                a[1] = __hadd2(a[1], u2h2(v4.y));
                a[2] = __hadd2(a[2], u2h2(v4.z));
                a[3] = __hadd2(a[3], u2h2(v4.w));
            }
            uint o[4];
#pragma unroll
            for (int k = 0; k < 4; k++) o[k] = h2u(a[k]);
            *(uint4*)(CAy + ((size_t)b * HWp + (y0 + p) * 48 + x) * (size_t)NSLOT + slot0) =
                *(const uint4*)o;
        }
    }
}

// ---------- gemm4s: P = CAy * bgT3^T, single 128x192 tile, split-K=8, fp16 partials ----------
__global__ __launch_bounds__(256) void gemm4s(const ushort* __restrict__ Am,
                                              const ushort* __restrict__ Bm,
                                              __half* __restrict__ aclp) {
    __shared__ ushort As[2 * 4096];
    __shared__ ushort Bs[2 * 6144];
    int i0 = blockIdx.x;                  // 576
    int b = (i0 & 7) >> 1;                // batch pinned to XCD pair
    int t2 = ((i0 >> 3) << 1) | (i0 & 1); // 0..143, bijective
    int s = t2 & 7, mt = t2 >> 3;         // 8 splits x 18 m-tiles
    int m0 = mt * 128;
    const int KB[9] = {0, 288, 576, 864, 1152, 1440, 1696, 1952, 2208};
    int kb = KB[s], ke = KB[s + 1];
    const ushort* Ab = Am + ((size_t)b * HWp + m0) * (size_t)NSLOT;
    const ushort* Bb = Bm + (size_t)b * 192 * (size_t)NSLOT;

    int tid = threadIdx.x;
    int l = tid & 63, w = tid >> 6;
    int quad = l >> 4, l15 = l & 15;
    int sw8 = (l15 >> 1) & 3;
    int wm = (w >> 1) * 64, wn = (w & 1) * 96;
    int rowInC = l >> 2;
    int cSw = (l & 3) ^ ((l >> 3) & 3);
    int cS8 = cSw * 8;

    float4v acc[4][6];
#pragma unroll
    for (int i = 0; i < 4; i++)
#pragma unroll
        for (int j = 0; j < 6; j++) acc[i][j] = (float4v){0.f, 0.f, 0.f, 0.f};

#pragma unroll
    for (int i = 0; i < 2; i++) {
        int rg = w * 2 + i;
        gld16(Ab + (size_t)(rg * 16 + rowInC) * NSLOT + kb + cS8, As + rg * 512);
    }
#pragma unroll
    for (int i = 0; i < 3; i++) {
        int rg = w * 3 + i;
        gld16(Bb + (size_t)(rg * 16 + rowInC) * NSLOT + kb + cS8, Bs + rg * 512);
    }

    int buf = 0;
    for (int k0 = kb; k0 < ke; k0 += 32) {
        __syncthreads();
        int nb = buf ^ 1;
        if (k0 + 32 < ke) {
#pragma unroll
            for (int i = 0; i < 2; i++) {
                int rg = w * 2 + i;
                gld16(Ab + (size_t)(rg * 16 + rowInC) * NSLOT + (k0 + 32) + cS8,
                      As + nb * 4096 + rg * 512);
            }
#pragma unroll
            for (int i = 0; i < 3; i++) {
                int rg = w * 3 + i;
                gld16(Bb + (size_t)(rg * 16 + rowInC) * NSLOT + (k0 + 32) + cS8,
                      Bs + nb * 6144 + rg * 512);
            }
        }
        const ushort* Ax = As + buf * 4096;
        const ushort* Bx = Bs + buf * 6144;
        half8 af[4], bf[6];
#pragma unroll
        for (int i = 0; i < 4; i++)
            af[i] = *(const half8*)&Ax[(wm + i * 16 + l15) * 32 + ((quad ^ sw8)) * 8];
#pragma unroll
        for (int j = 0; j < 6; j++)
            bf[j] = *(const half8*)&Bx[(wn + j * 16 + l15) * 32 + ((quad ^ sw8)) * 8];
#pragma unroll
        for (int i = 0; i < 4; i++)
#pragma unroll
            for (int j = 0; j < 6; j++)
                acc[i][j] = __builtin_amdgcn_mfma_f32_16x16x32_f16(af[i], bf[j], acc[i][j], 0, 0, 0);
        buf = nb;
    }

    __half* C = aclp + (size_t)b * HWp * 1536 + (size_t)s * 192;
#pragma unroll
    for (int i = 0; i < 4; i++)
#pragma unroll
        for (int j = 0; j < 6; j++)
#pragma unroll
            for (int r = 0; r < 4; r++) {
                int m = m0 + wm + i * 16 + quad * 4 + r;
                int n = wn + j * 16 + l15;
                C[(size_t)m * 1536 + n] = __float2half(acc[i][j][r]);
            }
}

// ---------- final: acl = sum_dx sum_s P[(y,x+1-dx)][s][dx*64+d]; wave-uniform mask skip ----------
__global__ __launch_bounds__(256) void final_k5(const float* __restrict__ g,
                                                const float* __restrict__ mask,
                                                const __half* __restrict__ aclp,
                                                const float* __restrict__ W2,
                                                const float* __restrict__ b2,
                                                float* __restrict__ out) {
    int w = threadIdx.x >> 6, d = threadIdx.x & 63;
    int pix = blockIdx.x * 4 + w;
    int b = pix / HWp, yx = pix % HWp;
    int y = yx / WW, x = yx % WW;

    __shared__ float con1[4][128];
    float m = mask[pix];
    float gv = g[(size_t)pix * DD + d];
    float bgv = gv * m;

    float acl = 0.f;
    if (m < 0.5f) {                      // mask==1 pixels never need acl (exact skip)
#pragma unroll
        for (int dx = 0; dx < 3; dx++) {
            int xs = x + 1 - dx;
            if (xs >= 0 && xs < WW) {
                const __half* p = aclp + ((size_t)b * HWp + y * WW + xs) * 1536 + dx * 64 + d;
#pragma unroll
                for (int s = 0; s < 8; s++) acl += __half2float(p[s * 192]);
            }
        }
    }

    float ACL = bgv + (acl / 9.f) * (1.f - m);
    con1[w][d] = gv;
    con1[w][64 + d] = ACL;
    __syncthreads();
    float accv = b2[d];
#pragma unroll 8
    for (int k = 0; k < 128; k++) accv = fmaf(con1[w][k], W2[k * 64 + d], accv);
    out[(size_t)pix * DD + d] = accv > 0.f ? accv : expm1f(accv);
}

extern "C" void kernel_launch(void* const* d_in, const int* in_sizes, int n_in,
                              void* d_out, int out_size, void* d_ws, size_t ws_size,
                              hipStream_t stream) {
    const float* g    = (const float*)d_in[0];
    const float* mask = (const float*)d_in[1];
    const float* W2   = (const float*)d_in[2];
    const float* b2   = (const float*)d_in[3];
    float* out = (float*)d_out;
    char* ws = (char*)d_ws;

    ushort* gpad  = (ushort*)(ws + OFFB_GPAD);
    ushort* bgpad = (ushort*)(ws + OFFB_BGPAD);
    float*  e     = (float*) (ws + OFFB_E);
    float*  k1d   = (float*) (ws + OFFB_K1D);
    ushort* bgT3  = (ushort*)(ws + OFFB_BGT3);
    __half* Fbuf  = (__half*)(ws + OFFB_F);
    ushort* CAy   = (ushort*)(ws + OFFB_CAY);
    __half* aclp  = (__half*)(ws + OFFB_ACLP);

    build_pads<<<BB * PP / 4, 256, 0, stream>>>(g, mask, gpad, bgpad, e);
    build_bgt3_k1d<<<dim3(36, BB), 256, 0, stream>>>(bgpad, e, bgT3, k1d);

    fgemm<<<1440, 256, 0, stream>>>(gpad, bgpad, Fbuf);

    qrscay8<<<BB * HWp / 8, 320, 0, stream>>>(Fbuf, k1d, CAy);

    gemm4s<<<576, 256, 0, stream>>>(CAy, bgT3, aclp);

    final_k5<<<BB * HWp / 4, 256, 0, stream>>>(g, mask, aclp, W2, b2, out);
}

// Round 10
// 172.953 us; speedup vs baseline: 1.0524x; 1.0524x over previous
//
#include <hip/hip_runtime.h>
#include <hip/hip_fp16.h>
#include <math.h>

// Problem constants
#define BB 4
#define HH 48
#define WW 48
#define DD 64
#define CC 2116          // 46*46 true column count (softmax stats)
#define HWp (HH*WW)      // 2304
#define PW 50            // zero-padded field width
#define PP (PW*PW)       // 2500 padded pixels

// slot space: j padded per-row 46->48 -> K width 2208 (dummies are zero)
#define SLOTW 48
#define NSLOT 2208
#define NGRP 276         // 2208/8 groups of 8 slots
#define QW 2304          // F row width (v-domain = 48*48)
#define QROWS 2500       // F rows (u-domain = 50*50)

typedef __attribute__((ext_vector_type(8))) short short8;
typedef __attribute__((ext_vector_type(8))) _Float16 half8;
typedef __attribute__((ext_vector_type(4))) float float4v;

// ---------- workspace layout (byte offsets, all 16B-aligned) ----------
#define OFFB_GPAD  ((size_t)0)            // bf16 [B][2500][64]     1,280,000 B
#define OFFB_BGPAD ((size_t)1280000)      // bf16 [B][2500][64]     1,280,000 B
#define OFFB_E     ((size_t)2560000)      // f32  [B][2304]            36,864 B
#define OFFB_K1D   ((size_t)2596864)      // f32  [B][2208]            35,328 B
#define OFFB_BGT3  ((size_t)2632192)      // fp16 [B][192][2208]    3,391,488 B
#define OFFB_F     ((size_t)6023680)      // fp16 F [B][2500][2304] 46,080,000 B
#define OFFB_CA    ((size_t)52103680)     // fp16 CA [B][2304][2208] 40,697,856 B
#define OFFB_CAY   ((size_t)92801536)     // fp16 CAy [B][2304][2208] 40,697,856 B
#define OFFB_ACLP  ((size_t)133499392)    // fp16 [B*2304][8][192]  28,311,552 B
// total 161,810,944 B (ws allocation is 256 MiB)

// ---------- helpers ----------
__device__ __forceinline__ ushort f2bf(float x) {
    unsigned u = __float_as_uint(x);
    return (ushort)((u + 0x7FFFu + ((u >> 16) & 1u)) >> 16);
}

__device__ __forceinline__ float waveReduceSum(float x) {
#pragma unroll
    for (int o = 32; o > 0; o >>= 1) x += __shfl_down(x, o, 64);
    return x;
}

__device__ __forceinline__ __half2 u2h2(uint u) {
    union { uint u; __half2 h; } c; c.u = u; return c.h;
}
__device__ __forceinline__ uint h2u(__half2 h) {
    union { __half2 h; uint u; } c; c.h = h; return c.u;
}

// packed f32x2 -> bf16x2 (RNE), one instruction
__device__ __forceinline__ uint cvtpk_bf16(float lo, float hi) {
    uint r;
    asm("v_cvt_pk_bf16_f32 %0, %1, %2" : "=v"(r) : "v"(lo), "v"(hi));
    return r;
}

// exp(-50*tanh(z)) with tanh folded: = exp(-50 + 100/(e^{2z}+1))
__device__ __forceinline__ float softexp(float d, float mu, float isd) {
    float z = (d - mu) * isd;
    float E2 = __expf(z + z);
    float r = __builtin_amdgcn_rcpf(E2 + 1.f);
    return __expf(fmaf(100.f, r, -50.f));
}

// async 16B global->LDS (wave-uniform LDS base + lane*16)
typedef __attribute__((address_space(3))) void lds_void_t;
typedef __attribute__((address_space(1))) void gmem_void_t;
__device__ __forceinline__ void gld16(const ushort* g, ushort* lds) {
    __builtin_amdgcn_global_load_lds((gmem_void_t*)g, (lds_void_t*)lds, 16, 0, 0);
}

// ---------- build padded fields ----------
__global__ __launch_bounds__(256) void build_pads(const float* __restrict__ g,
                                                  const float* __restrict__ mask,
                                                  ushort* __restrict__ gpad,
                                                  ushort* __restrict__ bgpad,
                                                  float* __restrict__ e) {
    int w = threadIdx.x >> 6, c = threadIdx.x & 63;
    int q4 = blockIdx.x * 4 + w;         // [0, B*2500)
    int b = q4 / PP, q = q4 % PP;
    int yp = q / PW, xp = q % PW;
    size_t o = (size_t)q4 * DD + c;
    if (yp >= 1 && yp <= HH && xp >= 1 && xp <= WW) {
        int pix = (yp - 1) * WW + (xp - 1);
        float gv = g[((size_t)b * HWp + pix) * DD + c];
        float m  = mask[(size_t)b * HWp + pix];
        float bgv = gv * m;
        gpad[o]  = f2bf(gv);
        bgpad[o] = f2bf(bgv);
        float ss = waveReduceSum(bgv * bgv);
        if (c == 0) e[b * HWp + pix] = ss;
    } else {
        gpad[o] = 0;
        bgpad[o] = 0;
    }
}

// ---------- bgT3: fp16 [B][192][2208], row (dx*64+d)[v'] = bgI[v'+dx, d]; + k1d ----------
__global__ __launch_bounds__(256) void build_bgt3_k1d(const ushort* __restrict__ bgpad,
                                                      const float* __restrict__ e,
                                                      ushort* __restrict__ bgT3,
                                                      float* __restrict__ k1d) {
    int b = blockIdx.y;
    int t = threadIdx.x;
    if (blockIdx.x == 35) {
#pragma unroll 1
        for (int st = t; st < NSLOT; st += 256) {
            int jy = st / SLOTW, jx = st - jy * SLOTW;
            float s = 0.f;
            if (jx < 46) {
                const float* eb = e + (size_t)b * HWp + jy * WW + jx;
#pragma unroll
                for (int ddy = 0; ddy < 3; ddy++)
#pragma unroll
                    for (int ddx = 0; ddx < 3; ddx++) s += eb[ddy * WW + ddx];
            }
            k1d[(size_t)b * NSLOT + st] = s;
        }
        return;
    }
    __shared__ ushort T[66 * 65];
    int jt = blockIdx.x;                 // 0..34
    const ushort* src = bgpad + (size_t)b * PP * DD;
    int lr = t >> 3, c8 = (t & 7) * 8;
#pragma unroll
    for (int pass = 0; pass < 2; pass++) {
        int r = lr + pass * 32;
        int v = jt * 64 + r;
        int vy = v / 48, vx = v - vy * 48;
        uint4 d = *(const uint4*)(src + (size_t)((vy + 1) * PW + (vx + 1)) * DD + c8);
        ushort tmp[8];
        *(uint4*)tmp = d;
#pragma unroll
        for (int u = 0; u < 8; u++) {
            float f = __uint_as_float((uint)tmp[u] << 16);
            __half h = __float2half_rn(f);
            T[r * 65 + c8 + u] = *(ushort*)&h;
        }
    }
    if (t < 16) {                        // halo rows 64, 65
        int r = 64 + (t >> 3);
        int c8b = (t & 7) * 8;
        int v = jt * 64 + r;
        int vy = v / 48, vx = v - vy * 48;
        uint4 d = *(const uint4*)(src + (size_t)((vy + 1) * PW + (vx + 1)) * DD + c8b);
        ushort tmp[8];
        *(uint4*)tmp = d;
#pragma unroll
        for (int u = 0; u < 8; u++) {
            float f = __uint_as_float((uint)tmp[u] << 16);
            __half h = __float2half_rn(f);
            T[r * 65 + c8b + u] = *(ushort*)&h;
        }
    }
    __syncthreads();
#pragma unroll
    for (int pass = 0; pass < 2; pass++) {
        int c = lr + pass * 32;
        int j8 = (t & 7) * 8;
        int col0 = jt * 64 + j8;
        if (col0 < NSLOT) {
#pragma unroll
            for (int dx = 0; dx < 3; dx++) {
                ushort tmp[8];
#pragma unroll
                for (int u = 0; u < 8; u++) tmp[u] = T[(j8 + u + dx) * 65 + c];
                *(uint4*)(bgT3 + ((size_t)b * 192 + dx * 64 + c) * NSLOT + col0) =
                    *(const uint4*)tmp;
            }
        }
    }
}

// ---------- fgemm: F[u,v] = sum_dx Q[u+dx,v+dx] as a K=192 GEMM (contiguous k) ----------
__global__ __launch_bounds__(256) void fgemm(const ushort* __restrict__ gpad,
                                             const ushort* __restrict__ bgpad,
                                             __half* __restrict__ Fout) {
    __shared__ ushort As[2 * 4096];
    __shared__ ushort Bs[2 * 4096];
    int i0 = blockIdx.x;
    int b = (i0 & 7) >> 1;                    // batch pinned to XCD pair
    int tile = ((i0 >> 3) << 1) | (i0 & 1);   // 0..359, bijective
    int ty = tile / 18, tx = tile - ty * 18;  // 20 m-tiles x 18 n-tiles
    int m0 = ty * 128, n0 = tx * 128;
    const ushort* Ag = gpad + (size_t)b * PP * DD;
    const ushort* Bg = bgpad + (size_t)b * PP * DD;

    int tid = threadIdx.x;
    int l = tid & 63, w = tid >> 6;
    int quad = l >> 4, l15 = l & 15;
    int sw8 = (l15 >> 1) & 3;
    int wm = (w >> 1) * 64, wn = (w & 1) * 64;
    int rowInC = l >> 2;
    int cSw = (l & 3) ^ ((l >> 3) & 3);

    int baseA[2], baseB[2];
#pragma unroll
    for (int i = 0; i < 2; i++) {
        int rg = w * 2 + i;
        int r = rg * 16 + rowInC;
        int u = m0 + r; if (u > QROWS - 1) u = QROWS - 1;  // clamp; store-guarded
        int n = n0 + r;
        int vy = n / 48, vx = n - vy * 48;
        baseA[i] = u * DD + cSw * 8;
        baseB[i] = ((vy + 1) * PW + (vx + 1)) * DD + cSw * 8;
    }

    float4v acc[4][4];
#pragma unroll
    for (int i = 0; i < 4; i++)
#pragma unroll
        for (int j = 0; j < 4; j++) acc[i][j] = (float4v){0.f, 0.f, 0.f, 0.f};

#pragma unroll
    for (int i = 0; i < 2; i++) {
        int rg = w * 2 + i;
        gld16(Ag + baseA[i], As + rg * 512);
        gld16(Bg + baseB[i], Bs + rg * 512);
    }

    int buf = 0;
    for (int k0 = 0; k0 < 192; k0 += 32) {
        __syncthreads();
        int nb = buf ^ 1;
        if (k0 + 32 < 192) {
#pragma unroll
            for (int i = 0; i < 2; i++) {
                int rg = w * 2 + i;
                gld16(Ag + baseA[i] + (k0 + 32), As + nb * 4096 + rg * 512);
                gld16(Bg + baseB[i] + (k0 + 32), Bs + nb * 4096 + rg * 512);
            }
        }
        const ushort* Ax = As + buf * 4096;
        const ushort* Bx = Bs + buf * 4096;
        short8 af[4], bf[4];
#pragma unroll
        for (int i = 0; i < 4; i++)
            af[i] = *(const short8*)&Ax[(wm + i * 16 + l15) * 32 + ((quad ^ sw8)) * 8];
#pragma unroll
        for (int j = 0; j < 4; j++)
            bf[j] = *(const short8*)&Bx[(wn + j * 16 + l15) * 32 + ((quad ^ sw8)) * 8];
#pragma unroll
        for (int i = 0; i < 4; i++)
#pragma unroll
            for (int j = 0; j < 4; j++)
                acc[i][j] = __builtin_amdgcn_mfma_f32_16x16x32_bf16(af[i], bf[j], acc[i][j], 0, 0, 0);
        buf = nb;
    }

    __half* C = Fout + (size_t)b * QROWS * QW;
#pragma unroll
    for (int i = 0; i < 4; i++) {
#pragma unroll
        for (int j = 0; j < 4; j++) {
            int n = n0 + wn + j * 16 + l15;
#pragma unroll
            for (int r = 0; r < 4; r++) {
                int m = m0 + wm + i * 16 + quad * 4 + r;
                if (m < QROWS) C[(size_t)m * QW + n] = __float2half(acc[i][j][r]);
            }
        }
    }
}

// ---------- qrowsoft6: fused CS + softmax -> fp16 CA, LDS row staging ----------
// 4 y-consecutive pixels (fixed x). The 6 unique F rows are staged ONCE each into an
// LDS row buffer (double-buffered through registers); the 3 dy-shifted reads come
// from LDS. Global loads/thread: 12 -> ~6.3. Numerics identical to qrowsoft5.
__global__ __launch_bounds__(320) void qrowsoft6(const __half* __restrict__ F,
                                                 const float* __restrict__ k1d,
                                                 ushort* __restrict__ CA) {
    __shared__ ushort rowbuf[2304];   // one F row (4.6 KB)
    __shared__ float red[8 * 321];    // reduction scratch (10.3 KB)
    int i0 = blockIdx.x;
    int b = (i0 & 7) >> 1;                       // batch pinned to XCD pair
    int sub = ((i0 >> 3) << 1) | (i0 & 1);       // 0..575
    int yq = sub / 48, x = sub - yq * 48;
    int y0 = yq * 4;

    int t = threadIdx.x;
    bool act = (t < NGRP);
    int jy = t / 6, jxb = (t - jy * 6) * 8;
    int slot0 = jy * SLOTW + jxb;
    bool vc6 = act && (jxb == 40);               // group containing pad slots 46,47

    __half2 cs[4][4];
#pragma unroll
    for (int p = 0; p < 4; p++)
#pragma unroll
        for (int k = 0; k < 4; k++) cs[p][k] = u2h2(0u);

    float k1v[8] = {0.f, 0.f, 0.f, 0.f, 0.f, 0.f, 0.f, 0.f};
    if (act) {
        const float* k1 = k1d + (size_t)b * NSLOT + slot0;
        float4 ka = *(const float4*)k1;
        float4 kb = *(const float4*)(k1 + 4);
        k1v[0] = ka.x; k1v[1] = ka.y; k1v[2] = ka.z; k1v[3] = ka.w;
        k1v[4] = kb.x; k1v[5] = kb.y; k1v[6] = kb.z; k1v[7] = kb.w;
    }

    const __half* Fb = F + ((size_t)b * QROWS + (size_t)y0 * PW + x) * QW;
    uint4 vA = make_uint4(0, 0, 0, 0), vB = make_uint4(0, 0, 0, 0);
    if (t < 276) vA = *(const uint4*)(Fb + t * 8);
    if (t < 12)  vB = *(const uint4*)(Fb + 2208 + t * 8);
#pragma unroll
    for (int r = 0; r < 6; r++) {
        if (r > 0) __syncthreads();              // prev row's LDS reads complete
        if (t < 276) *(uint4*)&rowbuf[t * 8] = vA;
        if (t < 12)  *(uint4*)&rowbuf[2208 + t * 8] = vB;
        if (r + 1 < 6) {                         // prefetch next row (flies during consume)
            const __half* Rn = Fb + (size_t)(r + 1) * PW * QW;
            if (t < 276) vA = *(const uint4*)(Rn + t * 8);
            if (t < 12)  vB = *(const uint4*)(Rn + 2208 + t * 8);
        }
        __syncthreads();                         // rowbuf visible
        if (act) {
#pragma unroll
            for (int dy = 0; dy < 3; dy++) {
                int p = r - dy;
                if (p >= 0 && p < 4) {
                    uint4 v4 = *(const uint4*)&rowbuf[slot0 + 48 * dy];
                    cs[p][0] = __hadd2(cs[p][0], u2h2(v4.x));
                    cs[p][1] = __hadd2(cs[p][1], u2h2(v4.y));
                    cs[p][2] = __hadd2(cs[p][2], u2h2(v4.z));
                    cs[p][3] = __hadd2(cs[p][3], u2h2(v4.w));
                }
            }
        }
    }

    // purge pad-slot garbage (slots 46,47 of each jy row)
    if (vc6) {
#pragma unroll
        for (int p = 0; p < 4; p++) cs[p][3] = u2h2(0u);
    }

    // ---- phase A: per-pixel sum & sumsq of ds = k1 - 2*cs ----
#pragma unroll
    for (int p = 0; p < 4; p++) {
        float s1p = 0.f, s2p = 0.f;
#pragma unroll
        for (int k = 0; k < 4; k++) {
            float2 f = __half22float2(cs[p][k]);
            float d0 = k1v[2*k]   - 2.f * f.x;
            float d1 = k1v[2*k+1] - 2.f * f.y;
            s1p += d0 + d1;
            s2p = fmaf(d0, d0, fmaf(d1, d1, s2p));
        }
        red[p * 321 + t]       = act ? s1p : 0.f;
        red[(4 + p) * 321 + t] = act ? s2p : 0.f;
    }
    __syncthreads();
    if (t < 128) {
        int v = t >> 4, sb = t & 15;
        float s = 0.f;
#pragma unroll
        for (int k = 0; k < 20; k++) s += red[v * 321 + sb + 16 * k];
#pragma unroll
        for (int o = 8; o > 0; o >>= 1) s += __shfl_down(s, o, 16);
        if (sb == 0) red[v * 321 + 320] = s;
    }
    __syncthreads();
    float mu[4], isd[4];
#pragma unroll
    for (int p = 0; p < 4; p++) {
        float m = red[p * 321 + 320] * (1.f / (float)CC);
        float ex2 = red[(4 + p) * 321 + 320] * (1.f / (float)CC);
        mu[p] = m;
        isd[p] = rsqrtf(ex2 - m * m);
    }

    // ---- exp pass: pack unnormalized exp as bf16 pairs, accumulate es ----
    uint eb[4][4];
#pragma unroll
    for (int p = 0; p < 4; p++) {
        float es = 0.f;
#pragma unroll
        for (int k = 0; k < 4; k++) {
            float2 f = __half22float2(cs[p][k]);
            float d0 = k1v[2*k]   - 2.f * f.x;
            float d1 = k1v[2*k+1] - 2.f * f.y;
            if (k == 3 && vc6) { d0 = 1e9f; d1 = 1e9f; }
            float e0 = softexp(d0, mu[p], isd[p]);
            float e1 = softexp(d1, mu[p], isd[p]);
            es += e0 + e1;
            eb[p][k] = cvtpk_bf16(e0, e1);
        }
        red[p * 321 + t] = act ? es : 0.f;
    }
    __syncthreads();
    if (t < 64) {
        int v = t >> 4, sb = t & 15;
        float s = 0.f;
#pragma unroll
        for (int k = 0; k < 20; k++) s += red[v * 321 + sb + 16 * k];
#pragma unroll
        for (int o = 8; o > 0; o >>= 1) s += __shfl_down(s, o, 16);
        if (sb == 0) red[v * 321 + 320] = s;
    }
    __syncthreads();

    // ---- normalize and store fp16 CA ----
    if (act) {
#pragma unroll
        for (int p = 0; p < 4; p++) {
            float iz = __builtin_amdgcn_rcpf(red[p * 321 + 320]);
            uint o[4];
#pragma unroll
            for (int k = 0; k < 4; k++) {
                uint wv = eb[p][k];
                float lo = __uint_as_float(wv << 16) * iz;
                float hi = __uint_as_float(wv & 0xffff0000u) * iz;
                __half2 hh = __halves2half2(__float2half_rn(lo), __float2half_rn(hi));
                o[k] = *(uint*)&hh;
            }
            int pix = (y0 + p) * WW + x;
            ushort* wp = CA + ((size_t)b * HWp + pix) * (size_t)NSLOT + slot0;
            *(uint4*)wp = *(const uint4*)o;
        }
    }
}

// ---------- cay_k8: CAy = 3-point dy-combine of CA, LDS row staging, 8 outputs ----------
// Block = fixed x, 8 y-outputs; reads 10 CA rows ONCE each (1.25x amplification vs 3x).
// Rows iterated descending so each output accumulates dy = 0,1,2 (matches cay_k order).
__global__ __launch_bounds__(320) void cay_k8(const ushort* __restrict__ CAu,
                                              ushort* __restrict__ CAy) {
    __shared__ ushort rowbuf[2208];   // one CA row (4.4 KB)
    int i0 = blockIdx.x;              // 1152
    int b = (i0 & 7) >> 1;
    int sub = ((i0 >> 3) << 1) | (i0 & 1);       // 0..287
    int yo = sub / 48, x = sub - yo * 48;
    int y0 = yo * 8;

    int t = threadIdx.x;
    bool act = (t < NGRP);
    int jy = t / 6, jxb = (t - jy * 6) * 8;
    int slot0 = jy * SLOTW + jxb;

    const ushort* CAb = CAu + (size_t)b * HWp * (size_t)NSLOT;

    __half2 acc[8][4];
#pragma unroll
    for (int p = 0; p < 8; p++)
#pragma unroll
        for (int k = 0; k < 4; k++) acc[p][k] = u2h2(0u);

    // preload r=9 (yy = y0+8)
    uint4 vA = make_uint4(0, 0, 0, 0);
    {
        int yy = y0 + 8;
        if (yy < HH && t < 276)
            vA = *(const uint4*)(CAb + (size_t)(yy * 48 + x) * NSLOT + t * 8);
    }
#pragma unroll
    for (int r = 9; r >= 0; r--) {
        if (r < 9) __syncthreads();              // prev row's LDS reads complete
        if (t < 276) *(uint4*)&rowbuf[t * 8] = vA;
        if (r > 0) {                             // prefetch next row (r-1): yy = y0-2+r
            int yy = y0 - 2 + r;
            vA = make_uint4(0, 0, 0, 0);
            if (yy >= 0 && yy < HH && t < 276)
                vA = *(const uint4*)(CAb + (size_t)(yy * 48 + x) * NSLOT + t * 8);
        }
        __syncthreads();                         // rowbuf visible
        int yyr = y0 - 1 + r;
        if (act && yyr >= 0 && yyr < HH) {
#pragma unroll
            for (int dy = 0; dy < 3; dy++) {
                int p = r - 2 + dy;
                if (p >= 0 && p < 8 && jy >= dy) {
                    uint4 v4 = *(const uint4*)&rowbuf[slot0 - 48 * dy];
                    acc[p][0] = __hadd2(acc[p][0], u2h2(v4.x));
                    acc[p][1] = __hadd2(acc[p][1], u2h2(v4.y));
                    acc[p][2] = __hadd2(acc[p][2], u2h2(v4.z));
                    acc[p][3] = __hadd2(acc[p][3], u2h2(v4.w));
                }
            }
        }
    }

    if (act) {
#pragma unroll
        for (int p = 0; p < 8; p++) {
            uint o[4];
#pragma unroll
            for (int k = 0; k < 4; k++) o[k] = h2u(acc[p][k]);
            *(uint4*)(CAy + ((size_t)b * HWp + (y0 + p) * 48 + x) * (size_t)NSLOT + slot0) =
                *(const uint4*)o;
        }
    }
}

// ---------- gemm4s: P = CAy * bgT3^T, single 128x192 tile, split-K=8, fp16 partials ----------
__global__ __launch_bounds__(256) void gemm4s(const ushort* __restrict__ Am,
                                              const ushort* __restrict__ Bm,
                                              __half* __restrict__ aclp) {
    __shared__ ushort As[2 * 4096];
    __shared__ ushort Bs[2 * 6144];
    int i0 = blockIdx.x;                  // 576
    int b = (i0 & 7) >> 1;                // batch pinned to XCD pair
    int t2 = ((i0 >> 3) << 1) | (i0 & 1); // 0..143, bijective
    int s = t2 & 7, mt = t2 >> 3;         // 8 splits x 18 m-tiles
    int m0 = mt * 128;
    const int KB[9] = {0, 288, 576, 864, 1152, 1440, 1696, 1952, 2208};
    int kb = KB[s], ke = KB[s + 1];
    const ushort* Ab = Am + ((size_t)b * HWp + m0) * (size_t)NSLOT;
    const ushort* Bb = Bm + (size_t)b * 192 * (size_t)NSLOT;

    int tid = threadIdx.x;
    int l = tid & 63, w = tid >> 6;
    int quad = l >> 4, l15 = l & 15;
    int sw8 = (l15 >> 1) & 3;
    int wm = (w >> 1) * 64, wn = (w & 1) * 96;
    int rowInC = l >> 2;
    int cSw = (l & 3) ^ ((l >> 3) & 3);
    int cS8 = cSw * 8;

    float4v acc[4][6];
#pragma unroll
    for (int i = 0; i < 4; i++)
#pragma unroll
        for (int j = 0; j < 6; j++) acc[i][j] = (float4v){0.f, 0.f, 0.f, 0.f};

#pragma unroll
    for (int i = 0; i < 2; i++) {
        int rg = w * 2 + i;
        gld16(Ab + (size_t)(rg * 16 + rowInC) * NSLOT + kb + cS8, As + rg * 512);
    }
#pragma unroll
    for (int i = 0; i < 3; i++) {
        int rg = w * 3 + i;
        gld16(Bb + (size_t)(rg * 16 + rowInC) * NSLOT + kb + cS8, Bs + rg * 512);
    }

    int buf = 0;
    for (int k0 = kb; k0 < ke; k0 += 32) {
        __syncthreads();
        int nb = buf ^ 1;
        if (k0 + 32 < ke) {
#pragma unroll
            for (int i = 0; i < 2; i++) {
                int rg = w * 2 + i;
                gld16(Ab + (size_t)(rg * 16 + rowInC) * NSLOT + (k0 + 32) + cS8,
                      As + nb * 4096 + rg * 512);
            }
#pragma unroll
            for (int i = 0; i < 3; i++) {
                int rg = w * 3 + i;
                gld16(Bb + (size_t)(rg * 16 + rowInC) * NSLOT + (k0 + 32) + cS8,
                      Bs + nb * 6144 + rg * 512);
            }
        }
        const ushort* Ax = As + buf * 4096;
        const ushort* Bx = Bs + buf * 6144;
        half8 af[4], bf[6];
#pragma unroll
        for (int i = 0; i < 4; i++)
            af[i] = *(const half8*)&Ax[(wm + i * 16 + l15) * 32 + ((quad ^ sw8)) * 8];
#pragma unroll
        for (int j = 0; j < 6; j++)
            bf[j] = *(const half8*)&Bx[(wn + j * 16 + l15) * 32 + ((quad ^ sw8)) * 8];
#pragma unroll
        for (int i = 0; i < 4; i++)
#pragma unroll
            for (int j = 0; j < 6; j++)
                acc[i][j] = __builtin_amdgcn_mfma_f32_16x16x32_f16(af[i], bf[j], acc[i][j], 0, 0, 0);
        buf = nb;
    }

    __half* C = aclp + (size_t)b * HWp * 1536 + (size_t)s * 192;
#pragma unroll
    for (int i = 0; i < 4; i++)
#pragma unroll
        for (int j = 0; j < 6; j++)
#pragma unroll
            for (int r = 0; r < 4; r++) {
                int m = m0 + wm + i * 16 + quad * 4 + r;
                int n = wn + j * 16 + l15;
                C[(size_t)m * 1536 + n] = __float2half(acc[i][j][r]);
            }
}

// ---------- final: acl = sum_dx sum_s P[(y,x+1-dx)][s][dx*64+d]; wave-uniform mask skip ----------
__global__ __launch_bounds__(256) void final_k5(const float* __restrict__ g,
                                                const float* __restrict__ mask,
                                                const __half* __restrict__ aclp,
                                                const float* __restrict__ W2,
                                                const float* __restrict__ b2,
                                                float* __restrict__ out) {
    int w = threadIdx.x >> 6, d = threadIdx.x & 63;
    int pix = blockIdx.x * 4 + w;
    int b = pix / HWp, yx = pix % HWp;
    int y = yx / WW, x = yx % WW;

    __shared__ float con1[4][128];
    float m = mask[pix];
    float gv = g[(size_t)pix * DD + d];
    float bgv = gv * m;

    float acl = 0.f;
    if (m < 0.5f) {                      // mask==1 pixels never need acl (exact skip)
#pragma unroll
        for (int dx = 0; dx < 3; dx++) {
            int xs = x + 1 - dx;
            if (xs >= 0 && xs < WW) {
                const __half* p = aclp + ((size_t)b * HWp + y * WW + xs) * 1536 + dx * 64 + d;
#pragma unroll
                for (int s = 0; s < 8; s++) acl += __half2float(p[s * 192]);
            }
        }
    }

    float ACL = bgv + (acl / 9.f) * (1.f - m);
    con1[w][d] = gv;
    con1[w][64 + d] = ACL;
    __syncthreads();
    float accv = b2[d];
#pragma unroll 8
    for (int k = 0; k < 128; k++) accv = fmaf(con1[w][k], W2[k * 64 + d], accv);
    out[(size_t)pix * DD + d] = accv > 0.f ? accv : expm1f(accv);
}

extern "C" void kernel_launch(void* const* d_in, const int* in_sizes, int n_in,
                              void* d_out, int out_size, void* d_ws, size_t ws_size,
                              hipStream_t stream) {
    const float* g    = (const float*)d_in[0];
    const float* mask = (const float*)d_in[1];
    const float* W2   = (const float*)d_in[2];
    const float* b2   = (const float*)d_in[3];
    float* out = (float*)d_out;
    char* ws = (char*)d_ws;

    ushort* gpad  = (ushort*)(ws + OFFB_GPAD);
    ushort* bgpad = (ushort*)(ws + OFFB_BGPAD);
    float*  e     = (float*) (ws + OFFB_E);
    float*  k1d   = (float*) (ws + OFFB_K1D);
    ushort* bgT3  = (ushort*)(ws + OFFB_BGT3);
    __half* Fbuf  = (__half*)(ws + OFFB_F);
    ushort* CA    = (ushort*)(ws + OFFB_CA);
    ushort* CAy   = (ushort*)(ws + OFFB_CAY);
    __half* aclp  = (__half*)(ws + OFFB_ACLP);

    build_pads<<<BB * PP / 4, 256, 0, stream>>>(g, mask, gpad, bgpad, e);
    build_bgt3_k1d<<<dim3(36, BB), 256, 0, stream>>>(bgpad, e, bgT3, k1d);

    fgemm<<<1440, 256, 0, stream>>>(gpad, bgpad, Fbuf);

    qrowsoft6<<<BB * HWp / 4, 320, 0, stream>>>(Fbuf, k1d, CA);

    cay_k8<<<BB * HWp / 8, 320, 0, stream>>>(CA, CAy);

    gemm4s<<<576, 256, 0, stream>>>(CAy, bgT3, aclp);

    final_k5<<<BB * HWp / 4, 256, 0, stream>>>(g, mask, aclp, W2, b2, out);
}